// Round 1
// 822.409 us; speedup vs baseline: 1.1407x; 1.1407x over previous
//
#include <hip/hip_runtime.h>

__device__ __forceinline__ float sigmoidf_(float x){ return 1.f/(1.f+__expf(-x)); }

// ---------- CSR build (proven in R5) ----------
__global__ void hist_kernel(const int* __restrict__ dst, int* __restrict__ cnt, int E){
  int e = blockIdx.x*blockDim.x + threadIdx.x;
  if (e < E) atomicAdd(&cnt[dst[e]], 1);
}

// cnt and wptr may ALIAS: cnt[i] read before wptr[i] written (same thread).
__global__ __launch_bounds__(1024) void scan_kernel(const int* __restrict__ cnt,
                                                    int* __restrict__ off,
                                                    int* __restrict__ wptr, int N){
  __shared__ int part[1024];
  const int t = threadIdx.x;
  const int chunk = (N + 1023) / 1024;
  const int lo = min(t*chunk, N), hi = min(lo+chunk, N);
  int s = 0;
  for (int i = lo; i < hi; i++) s += cnt[i];
  part[t] = s;
  __syncthreads();
  for (int o = 1; o < 1024; o <<= 1){
    int v = (t >= o) ? part[t-o] : 0;
    __syncthreads();
    part[t] += v;
    __syncthreads();
  }
  int run = part[t] - s;
  for (int i = lo; i < hi; i++){
    int c = cnt[i];
    off[i] = run; wptr[i] = run;
    run += c;
  }
  if (t == 1023) off[N] = part[1023];
}

__global__ void scatter_kernel(const int* __restrict__ dst, int* __restrict__ wptr,
                               int* __restrict__ csr, int E){
  int e = blockIdx.x*blockDim.x + threadIdx.x;
  if (e < E){
    int pos = atomicAdd(&wptr[dst[e]], 1);
    csr[pos] = e;
  }
}

// ---------- Edge phase v2 (unchanged this round): node-centric gather ----------
__global__ __launch_bounds__(128) void edge_agg_kernel(
    const float* __restrict__ edge_s, const float* __restrict__ edge_v,
    const int* __restrict__ csr, const int* __restrict__ off,
    const float* __restrict__ wes, const float* __restrict__ bes,
    const float* __restrict__ wev, const float* __restrict__ bev,
    float* __restrict__ aggS, float* __restrict__ aggV, int N)
{
  const int t = threadIdx.x;
  float w[32];
  #pragma unroll
  for (int k = 0; k < 32; k += 4){
    float4 u = *(const float4*)(wes + t*32 + k);
    w[k]=u.x; w[k+1]=u.y; w[k+2]=u.z; w[k+3]=u.w;
  }
  const float bt = bes[t];
  const bool w0 = (t < 64);
  float wv0=0.f, wv1=0.f, wv2=0.f, bv=0.f;
  if (t < 48){ wv0=wev[t*3]; wv1=wev[t*3+1]; wv2=wev[t*3+2]; bv=bev[t]; }

  const int i = blockIdx.x;
  if (i >= N) return;
  const int jb = off[i], je = off[i+1];

  float accS = 0.f, accV = 0.f;
  if (jb < je){
    int e = csr[jb];
    float4 cur[8];
    {
      const float4* pr = (const float4*)(edge_s + (size_t)e*32);
      #pragma unroll
      for (int q = 0; q < 8; q++) cur[q] = pr[q];
    }
    float vx=0.f, vy=0.f, vz=0.f;
    if (w0){ const float* pv = edge_v + (size_t)e*3; vx=pv[0]; vy=pv[1]; vz=pv[2]; }

    for (int j = jb; j < je; j++){
      const int en = (j+1 < je) ? csr[j+1] : e;
      float4 nxt[8];
      {
        const float4* pn = (const float4*)(edge_s + (size_t)en*32);
        #pragma unroll
        for (int q = 0; q < 8; q++) nxt[q] = pn[q];
      }
      float nx=0.f, ny=0.f, nz=0.f;
      if (w0){ const float* pv = edge_v + (size_t)en*3; nx=pv[0]; ny=pv[1]; nz=pv[2]; }

      float d0 = 0.f, d1 = 0.f;
      #pragma unroll
      for (int q = 0; q < 8; q += 2){
        d0 += cur[q].x*w[4*q+0] + cur[q].y*w[4*q+1] + cur[q].z*w[4*q+2] + cur[q].w*w[4*q+3];
        d1 += cur[q+1].x*w[4*q+4] + cur[q+1].y*w[4*q+5] + cur[q+1].z*w[4*q+6] + cur[q+1].w*w[4*q+7];
      }
      const float acc = bt + d0 + d1;
      const float sil = acc * sigmoidf_(acc);      // silu
      accS += sil;
      if (w0){
        float g = __shfl(sil, (t < 48) ? (t/3) : 0, 64);
        if (t < 48) accV += (bv + wv0*vx + wv1*vy + wv2*vz) * sigmoidf_(g);
      }
      #pragma unroll
      for (int q = 0; q < 8; q++) cur[q] = nxt[q];
      vx=nx; vy=ny; vz=nz;
    }
  }
  const float rdn = 1.f / (float)max(je - jb, 1);  // scatter-mean
  aggS[(size_t)i*128 + t] = accS * rdn;
  if (t < 48) aggV[(size_t)i*48 + t] = accV * rdn;
}

// ---------- Node phase v3: 64-node tiles, full-wave-uniform (scalar) weights ----------
// lane = node across the full 64-lane wave; each of 8 waves owns 16 output
// channels, so every weight address is wave-uniform -> compiler emits s_load
// (scalar path, no VMEM latency on the critical loop). K is staged in two
// 64-wide halves so LDS stays at ~39 KB. Stride 68: b128 reads at the 8-phase
// structural minimum, zero extra bank conflicts.
#define NS_RS 68
#define NS_GS 17

__global__ __launch_bounds__(512, 4) void node_kernel(
    const float* __restrict__ node_s, const float* __restrict__ node_v,
    const float* __restrict__ ln_g, const float* __restrict__ ln_b,
    const float* __restrict__ wns, const float* __restrict__ bns,
    const float* __restrict__ wnv, const float* __restrict__ bnv,
    const float* __restrict__ wrs, const float* __restrict__ brs,
    const float* __restrict__ wrv, const float* __restrict__ brv,
    const float* __restrict__ aggS, const float* __restrict__ aggV,
    float* __restrict__ out_s, float* __restrict__ out_v, int N)
{
  __shared__ float shX[64*NS_RS];        // inS = sn + aggS   (current k-half)
  __shared__ float shS[64*NS_RS];        // sn                (current k-half)
  __shared__ float shP1[128], shP2[128]; // LN partial sums (2 k-halves)
  __shared__ float shGate[64*NS_GS];

  const int tid  = threadIdx.x;
  const int lane = tid & 63;
  const int wv   = __builtin_amdgcn_readfirstlane(tid >> 6);   // 0..7, SGPR
  const int i0   = blockIdx.x * 64;
  const int node = i0 + lane;

  // ---- LN stats: waves 0,1 each sum one k-half, lane = node ----
  if (wv < 2){
    float s1 = 0.f, s2 = 0.f;
    if (node < N){
      const float4* p = (const float4*)(node_s + (size_t)node*128 + wv*64);
      #pragma unroll
      for (int q = 0; q < 16; q++){
        const float4 v = p[q];
        s1 += (v.x+v.y)+(v.z+v.w);
        s2 += (v.x*v.x+v.y*v.y)+(v.z*v.z+v.w*v.w);
      }
    }
    shP1[wv*64+lane] = s1;
    shP2[wv*64+lane] = s2;
  }
  __syncthreads();

  float acc1[16], acc2[16];
  #pragma unroll
  for (int j = 0; j < 16; j++){ acc1[j]=0.f; acc2[j]=0.f; }
  const int cb = wv*16;

  for (int half = 0; half < 2; half++){
    const int kb = half*64;
    // ---- stage 64 nodes x 64 k: normalized (+agg) ----
    {
      const int n  = tid >> 3;           // 0..63
      const int kk = (tid & 7)*8;        // 0..56
      const int gn = i0 + n;
      const float s1 = shP1[n] + shP1[64+n];
      const float s2 = shP2[n] + shP2[64+n];
      const float m  = s1 * (1.f/128.f);
      const float r  = rsqrtf(s2*(1.f/128.f) - m*m + 1e-5f);
      float4 x0 = make_float4(0.f,0.f,0.f,0.f), x1 = x0, a0 = x0, a1v = x0;
      if (gn < N){
        const float4* ps = (const float4*)(node_s + (size_t)gn*128 + kb + kk);
        x0 = ps[0]; x1 = ps[1];
        const float4* pa = (const float4*)(aggS + (size_t)gn*128 + kb + kk);
        a0 = pa[0]; a1v = pa[1];
      }
      const float4 g0 = *(const float4*)(ln_g + kb + kk);
      const float4 g1 = *(const float4*)(ln_g + kb + kk + 4);
      const float4 b0 = *(const float4*)(ln_b + kb + kk);
      const float4 b1 = *(const float4*)(ln_b + kb + kk + 4);
      const float sn0 = (x0.x-m)*r*g0.x + b0.x;
      const float sn1 = (x0.y-m)*r*g0.y + b0.y;
      const float sn2 = (x0.z-m)*r*g0.z + b0.z;
      const float sn3 = (x0.w-m)*r*g0.w + b0.w;
      const float sn4 = (x1.x-m)*r*g1.x + b1.x;
      const float sn5 = (x1.y-m)*r*g1.y + b1.y;
      const float sn6 = (x1.z-m)*r*g1.z + b1.z;
      const float sn7 = (x1.w-m)*r*g1.w + b1.w;
      float* pS = &shS[n*NS_RS + kk];
      float* pX = &shX[n*NS_RS + kk];
      ((float4*)pS)[0] = make_float4(sn0,sn1,sn2,sn3);
      ((float4*)pS)[1] = make_float4(sn4,sn5,sn6,sn7);
      ((float4*)pX)[0] = make_float4(sn0+a0.x, sn1+a0.y, sn2+a0.z, sn3+a0.w);
      ((float4*)pX)[1] = make_float4(sn4+a1v.x, sn5+a1v.y, sn6+a1v.z, sn7+a1v.w);
    }
    __syncthreads();

    // ---- scalar GEMVs: wave-uniform weight rows (s_load), lane = node ----
    for (int kc = 0; kc < 64; kc += 8){
      const float4 xa = ((const float4*)&shX[lane*NS_RS + kc])[0];
      const float4 xb = ((const float4*)&shX[lane*NS_RS + kc])[1];
      const float4 sa = ((const float4*)&shS[lane*NS_RS + kc])[0];
      const float4 sb = ((const float4*)&shS[lane*NS_RS + kc])[1];
      #pragma unroll
      for (int j = 0; j < 16; j++){
        const float* w1 = wns + (size_t)(cb+j)*128 + kb + kc;
        const float* w2 = wrs + (size_t)(cb+j)*128 + kb + kc;
        const float4 u0 = ((const float4*)w1)[0], u1 = ((const float4*)w1)[1];
        const float4 y0 = ((const float4*)w2)[0], y1 = ((const float4*)w2)[1];
        acc1[j] += (xa.x*u0.x + xa.y*u0.y + xa.z*u0.z + xa.w*u0.w)
                 + (xb.x*u1.x + xb.y*u1.y + xb.z*u1.z + xb.w*u1.w);
        acc2[j] += (sa.x*y0.x + sa.y*y0.y + sa.z*y0.z + sa.w*y0.w)
                 + (sb.x*y1.x + sb.y*y1.y + sb.z*y1.z + sb.w*y1.w);
      }
    }
    __syncthreads();   // before restage (half=1) / before gate write (exit)
  }

  // ---- scalar epilogue: silu + gate + residual, contiguous float4 stores ----
  {
    float o[16];
    #pragma unroll
    for (int j = 0; j < 16; j++){
      const float aa = acc1[j] + bns[cb+j];
      const float so = aa * sigmoidf_(aa);          // silu
      if (wv == 0) shGate[lane*NS_GS + j] = sigmoidf_(so);
      o[j] = so + acc2[j] + brs[cb+j];
    }
    if (node < N){
      float4* po = (float4*)(out_s + (size_t)node*128 + cb);
      #pragma unroll
      for (int q = 0; q < 4; q++)
        po[q] = make_float4(o[4*q],o[4*q+1],o[4*q+2],o[4*q+3]);
    }
  }
  __syncthreads();   // gate ready

  // ---- vector GEMVs: fully register-resident per lane, s_load weights ----
  {
    const int vb = wv*6;                 // 8 waves x 6 = 48 channels
    float sv[48];
    float s3 = 0.f;
    if (node < N){
      const float4* pv = (const float4*)(node_v + (size_t)node*48);
      #pragma unroll
      for (int q = 0; q < 12; q++){
        const float4 v = pv[q];
        sv[4*q]=v.x; sv[4*q+1]=v.y; sv[4*q+2]=v.z; sv[4*q+3]=v.w;
        s3 += (v.x*v.x+v.y*v.y)+(v.z*v.z+v.w*v.w);
      }
    } else {
      #pragma unroll
      for (int k = 0; k < 48; k++) sv[k]=0.f;
    }
    const float rvn = rsqrtf(s3*(1.f/16.f) + 1e-8f);
    #pragma unroll
    for (int k = 0; k < 48; k++) sv[k] *= rvn;     // sv = vn

    float a1[6], a2[6];
    #pragma unroll
    for (int j = 0; j < 6; j++){ a1[j]=0.f; a2[j]=0.f; }

    #pragma unroll
    for (int kc = 0; kc < 48; kc += 8){
      float xv[8];
      if (node < N){
        const float4* pa = (const float4*)(aggV + (size_t)node*48 + kc);
        const float4 av0 = pa[0], av1 = pa[1];
        xv[0]=sv[kc]+av0.x;   xv[1]=sv[kc+1]+av0.y;
        xv[2]=sv[kc+2]+av0.z; xv[3]=sv[kc+3]+av0.w;
        xv[4]=sv[kc+4]+av1.x; xv[5]=sv[kc+5]+av1.y;
        xv[6]=sv[kc+6]+av1.z; xv[7]=sv[kc+7]+av1.w;
      } else {
        #pragma unroll
        for (int q = 0; q < 8; q++) xv[q] = 0.f;
      }
      #pragma unroll
      for (int j = 0; j < 6; j++){
        const float* w1 = wnv + (size_t)(vb+j)*48 + kc;
        const float* w2 = wrv + (size_t)(vb+j)*48 + kc;
        const float4 u0 = ((const float4*)w1)[0], u1 = ((const float4*)w1)[1];
        const float4 y0 = ((const float4*)w2)[0], y1 = ((const float4*)w2)[1];
        a1[j] += (xv[0]*u0.x + xv[1]*u0.y + xv[2]*u0.z + xv[3]*u0.w)
               + (xv[4]*u1.x + xv[5]*u1.y + xv[6]*u1.z + xv[7]*u1.w);
        a2[j] += (sv[kc]*y0.x + sv[kc+1]*y0.y + sv[kc+2]*y0.z + sv[kc+3]*y0.w)
               + (sv[kc+4]*y1.x + sv[kc+5]*y1.y + sv[kc+6]*y1.z + sv[kc+7]*y1.w);
      }
    }
    if (node < N){
      const float g0 = shGate[lane*NS_GS + 2*wv];
      const float g1 = shGate[lane*NS_GS + 2*wv + 1];
      float ov[6];
      #pragma unroll
      for (int j = 0; j < 6; j++){
        const float g = (j < 3) ? g0 : g1;
        ov[j] = (a1[j] + bnv[vb+j])*g + a2[j] + brv[vb+j];
      }
      float2* po = (float2*)(out_v + (size_t)node*48 + vb);
      po[0] = make_float2(ov[0], ov[1]);
      po[1] = make_float2(ov[2], ov[3]);
      po[2] = make_float2(ov[4], ov[5]);
    }
  }
}

extern "C" void kernel_launch(void* const* d_in, const int* in_sizes, int n_in,
                              void* d_out, int out_size, void* d_ws, size_t ws_size,
                              hipStream_t stream)
{
  const float* node_s = (const float*)d_in[0];
  const float* node_v = (const float*)d_in[1];
  const int*   eidx   = (const int*)  d_in[2];
  const float* edge_s = (const float*)d_in[3];
  const float* edge_v = (const float*)d_in[4];
  const float* ln_g   = (const float*)d_in[5];
  const float* ln_b   = (const float*)d_in[6];
  const float* wes    = (const float*)d_in[7];
  const float* bes    = (const float*)d_in[8];
  const float* wev    = (const float*)d_in[9];
  const float* bev    = (const float*)d_in[10];
  const float* wns    = (const float*)d_in[11];
  const float* bns    = (const float*)d_in[12];
  const float* wnv    = (const float*)d_in[13];
  const float* bnv    = (const float*)d_in[14];
  const float* wrs    = (const float*)d_in[15];
  const float* brs    = (const float*)d_in[16];
  const float* wrv    = (const float*)d_in[17];
  const float* brv    = (const float*)d_in[18];

  const int N = in_sizes[0] / 128;
  const int E = in_sizes[3] / 32;
  const int* dst = eidx + E;     // edge_index row 1

  // agg arrays in d_ws: N*176*4 = 35.2 MB (proven-safe footprint).
  float* aggS = (float*)d_ws;
  float* aggV = aggS + (size_t)N*128;

  // CSR scratch in the FRONT of d_out (3.6 MB); dead before node_kernel writes.
  int* off  = (int*)d_out;
  int* wptr = off + (N + 1);
  int* csr  = wptr + N;

  hipMemsetAsync(wptr, 0, (size_t)N*sizeof(int), stream);
  hist_kernel<<<(E+255)/256, 256, 0, stream>>>(dst, wptr, E);
  scan_kernel<<<1, 1024, 0, stream>>>(wptr, off, wptr, N);
  scatter_kernel<<<(E+255)/256, 256, 0, stream>>>(dst, wptr, csr, E);

  edge_agg_kernel<<<N, 128, 0, stream>>>(edge_s, edge_v, csr, off,
                                         wes, bes, wev, bev, aggS, aggV, N);

  float* out_s = (float*)d_out;
  float* out_v = out_s + (size_t)N*128;
  node_kernel<<<(N+63)/64, 512, 0, stream>>>(node_s, node_v, ln_g, ln_b,
                                             wns, bns, wnv, bnv,
                                             wrs, brs, wrv, brv,
                                             aggS, aggV, out_s, out_v, N);
}